// Round 8
// baseline (337.558 us; speedup 1.0000x reference)
//
#include <hip/hip_runtime.h>

#define CIN   64
#define NOUT  128
#define IMH   128
#define IMW   128
#define NPTS  9
#define NB    4
#define HW    (IMH*IMW)          // 16384
#define ROWS  (IMH*NPTS)         // 1152
#define CHS   (ROWS*IMW)         // 147456

typedef float    f32x4 __attribute__((ext_vector_type(4)));
typedef unsigned u32x4 __attribute__((ext_vector_type(4)));
typedef unsigned short ushort_t;

// fp32 -> bf16 round-to-nearest-even
__device__ __forceinline__ ushort_t f2bf(float f) {
    union { float f; unsigned u; } a; a.f = f;
    unsigned r = a.u + 0x7FFFu + ((a.u >> 16) & 1u);
    return (ushort_t)(r >> 16);
}

// 8 packed bf16 -> 8 fp32
__device__ __forceinline__ void cvt8(u32x4 v, float* f) {
    f[0] = __uint_as_float(v.x << 16); f[1] = __uint_as_float(v.x & 0xFFFF0000u);
    f[2] = __uint_as_float(v.y << 16); f[3] = __uint_as_float(v.y & 0xFFFF0000u);
    f[4] = __uint_as_float(v.z << 16); f[5] = __uint_as_float(v.z & 0xFFFF0000u);
    f[6] = __uint_as_float(v.w << 16); f[7] = __uint_as_float(v.w & 0xFFFF0000u);
}

// ---------------- Kernel A: 3x3 SAME conv, C=64 -> 18 (offsets) ----------------
__global__ __launch_bounds__(256) void k_offset(const float* __restrict__ x,
                                                const float* __restrict__ pw,
                                                const float* __restrict__ pb,
                                                float* __restrict__ off,
                                                float* __restrict__ stats0) {
    __shared__ float wl[576 * 20];        // [c*9+tap][k], stride 20
    __shared__ float red[3 * 64 * 19];

    int tid = threadIdx.x;
    if (blockIdx.x == 0) stats0[tid] = 0.f;   // gsum[128] + gsq[128]

    for (int t = tid; t < 18 * 576; t += 256) {
        int k = t / 576, cj = t % 576;    // pw layout [k][c][3][3]
        wl[cj * 20 + k] = pw[t];
    }
    __syncthreads();

    int cg = tid >> 6;
    int lp = tid & 63;
    int gid = blockIdx.x * 64 + lp;
    int b = gid >> 14;
    int hw = gid & 16383;
    int h = hw >> 7;
    int w = hw & 127;

    float acc[18];
#pragma unroll
    for (int k = 0; k < 18; ++k) acc[k] = (cg == 0) ? pb[k] : 0.f;

    const float* xb = x + (size_t)b * CIN * HW;
    int c0 = cg * 16;
    for (int c = c0; c < c0 + 16; ++c) {
        const float* xc = xb + c * HW;
#pragma unroll
        for (int dh = 0; dh < 3; ++dh) {
            int hh = h + dh - 1;
            if ((unsigned)hh >= 128u) continue;
#pragma unroll
            for (int dw = 0; dw < 3; ++dw) {
                int ww = w + dw - 1;
                if ((unsigned)ww >= 128u) continue;
                float xv = xc[hh * IMW + ww];
                const float* wr = &wl[(c * 9 + dh * 3 + dw) * 20];
                float wv[18];
                *(float4*)&wv[0]  = *(const float4*)(wr);
                *(float4*)&wv[4]  = *(const float4*)(wr + 4);
                *(float4*)&wv[8]  = *(const float4*)(wr + 8);
                *(float4*)&wv[12] = *(const float4*)(wr + 12);
                *(float2*)&wv[16] = *(const float2*)(wr + 16);
#pragma unroll
                for (int k = 0; k < 18; ++k) acc[k] += wv[k] * xv;
            }
        }
    }

    if (cg > 0) {
        float* rp = &red[((cg - 1) * 64 + lp) * 19];
#pragma unroll
        for (int k = 0; k < 18; ++k) rp[k] = acc[k];
    }
    __syncthreads();
    if (cg == 0) {
#pragma unroll
        for (int k = 0; k < 18; ++k)
            acc[k] += red[(0 * 64 + lp) * 19 + k] + red[(64 + lp) * 19 + k] + red[(128 + lp) * 19 + k];
        float* ob = off + (size_t)b * 18 * HW + hw;
#pragma unroll
        for (int k = 0; k < 18; ++k) ob[k * HW] = acc[k];
    }
}

// ---------------- Kernel Z: 1x1 conv, x[b][c][hw] -> z[b][hw][oc] (bf16) ----------------
__global__ __launch_bounds__(256) void k_z(const float* __restrict__ x,
                                           const float* __restrict__ cw,
                                           ushort_t* __restrict__ z) {
    __shared__ float xs[64 * 128];
    __shared__ float wsm[64 * 128];
    int tid = threadIdx.x;
    int b   = blockIdx.x >> 7;
    int hw0 = (blockIdx.x & 127) << 7;

    const float* xb = x + (size_t)b * CIN * HW + hw0;
#pragma unroll
    for (int i = 0; i < 32; ++i) {
        int t = tid + i * 256;
        int c = t >> 7, l = t & 127;
        xs[t] = xb[c * HW + l];
    }
#pragma unroll
    for (int i = 0; i < 32; ++i) {
        int t = tid + i * 256;
        int oc = t & 127, c = t >> 7;        // cw layout [oc][c]
        wsm[c * 128 + oc] = cw[oc * 64 + c];
    }
    __syncthreads();

    int hw4  = (tid & 31) << 2;
    int oc16 = (tid >> 5) << 4;

    float acc[4][16];
#pragma unroll
    for (int j = 0; j < 4; ++j)
#pragma unroll
        for (int k = 0; k < 16; ++k) acc[j][k] = 0.f;

    for (int c = 0; c < 64; ++c) {
        float4 xv = *(const float4*)&xs[c * 128 + hw4];
        float xq[4] = {xv.x, xv.y, xv.z, xv.w};
        float wv[16];
        const float4* wrow = (const float4*)&wsm[c * 128 + oc16];
#pragma unroll
        for (int m = 0; m < 4; ++m) ((float4*)wv)[m] = wrow[m];
#pragma unroll
        for (int j = 0; j < 4; ++j)
#pragma unroll
            for (int k = 0; k < 16; ++k) acc[j][k] += xq[j] * wv[k];
    }

#pragma unroll
    for (int j = 0; j < 4; ++j) {
        ushort_t* zr = z + ((size_t)b * HW + hw0 + hw4 + j) * NOUT + oc16;
        union { ushort_t u[16]; uint4 q[2]; } pk;
#pragma unroll
        for (int k = 0; k < 16; ++k) pk.u[k] = f2bf(acc[j][k]);
        *(uint4*)zr       = pk.q[0];
        *(uint4*)(zr + 8) = pk.q[1];
    }
}

// ---------------- bilinear coords for one (b,h,n,w) ----------------
__device__ __forceinline__ void bilin_setup(const float* __restrict__ off,
                                            int b, int h, int n, int w,
                                            float4& g, int4& id) {
    const float* ob = off + ((size_t)b * 18 + n) * HW + h * IMW + w;
    float ox = ob[0];
    float oy = ob[9 * HW];
    float px = ox + (float)(n / 3) + (float)h;
    float py = oy + (float)(n % 3) + (float)w;
    float fX = floorf(px), fY = floorf(py);
    float fx = px - fX, fy = py - fY;
    int X = (int)fX, Y = (int)fY;
    g.x = (1.f - fx) * (1.f - fy);   // lt (X,   Y)
    g.y = fx * fy;                   // rb (X+1, Y+1)
    g.z = (1.f - fx) * fy;           // lb (X,   Y+1)
    g.w = fx * (1.f - fy);           // rt (X+1, Y)
    id.x = min(max(X * IMW + Y, 0), HW - 1) * NOUT;
    id.y = min(max((X + 1) * IMW + (Y + 1), 0), HW - 1) * NOUT;
    id.z = min(max(X * IMW + (Y + 1), 0), HW - 1) * NOUT;
    id.w = min(max((X + 1) * IMW + Y, 0), HW - 1) * NOUT;
}

// XCD-aware bijective swizzle: 4608 = 8 XCDs x 576 contiguous logical blocks.
__device__ __forceinline__ int swz_block() {
    return (blockIdx.x & 7) * 576 + (blockIdx.x >> 3);
}

// ---------------- Kernel G: single gather pass — bilinear combine, BN sums,
//                  and bf16 a-buffer streamed out ([b][r][w][oc], NT) ----------------
__global__ __launch_bounds__(256) void k_gather(const float* __restrict__ off,
                                                const ushort_t* __restrict__ z,
                                                ushort_t* __restrict__ abuf,
                                                float* __restrict__ gsum,
                                                float* __restrict__ gsq) {
    int logical = swz_block();
    int n  = logical % 9;
    int t2 = logical / 9;
    int h  = t2 & 127;
    int b  = t2 >> 7;

    __shared__ float4 gS[128];
    __shared__ int4   iS[128];
    __shared__ float  lsum[128];
    __shared__ float  lsq[128];

    int tid = threadIdx.x;
    if (tid < 128) {
        lsum[tid] = 0.f; lsq[tid] = 0.f;
        float4 g; int4 id;
        bilin_setup(off, b, h, n, tid, g, id);
        gS[tid] = g; iS[tid] = id;
    }
    __syncthreads();

    int g16 = tid >> 4;              // 0..15: w sub-slot
    int c8  = (tid & 15) << 3;       // 8 consecutive channels
    const ushort_t* zb = z + (size_t)b * HW * NOUT + c8;
    int r = h * 9 + n;
    ushort_t* ab = abuf + ((size_t)(b * ROWS + r)) * IMW * NOUT + c8;

    float s[8], q[8];
#pragma unroll
    for (int k = 0; k < 8; ++k) { s[k] = 0.f; q[k] = 0.f; }

#pragma unroll
    for (int wi = 0; wi < 8; ++wi) {
        int w = (wi << 4) + g16;
        int4  id = iS[w];
        float4 g = gS[w];
        u32x4 vlt = *(const u32x4*)(zb + id.x);
        u32x4 vrb = *(const u32x4*)(zb + id.y);
        u32x4 vlb = *(const u32x4*)(zb + id.z);
        u32x4 vrt = *(const u32x4*)(zb + id.w);
        float flt[8], frb[8], flb[8], frt[8];
        cvt8(vlt, flt); cvt8(vrb, frb); cvt8(vlb, flb); cvt8(vrt, frt);
        float a[8];
#pragma unroll
        for (int k = 0; k < 8; ++k) {
            a[k] = g.x * flt[k] + g.y * frb[k] + g.z * flb[k] + g.w * frt[k];
            s[k] += a[k]; q[k] += a[k] * a[k];
        }
        union { ushort_t u[8]; u32x4 v; } pk;
#pragma unroll
        for (int k = 0; k < 8; ++k) pk.u[k] = f2bf(a[k]);
        __builtin_nontemporal_store(pk.v, (u32x4*)(ab + (size_t)w * NOUT));
    }

    // reduce across the 4 w-subgroups sharing channels (lanes tid^16, tid^32)
#pragma unroll
    for (int k = 0; k < 8; ++k) {
        s[k] += __shfl_xor(s[k], 16, 64); s[k] += __shfl_xor(s[k], 32, 64);
        q[k] += __shfl_xor(q[k], 16, 64); q[k] += __shfl_xor(q[k], 32, 64);
    }
    if (((tid >> 4) & 3) == 0) {
#pragma unroll
        for (int k = 0; k < 8; ++k) {
            atomicAdd(&lsum[c8 + k], s[k]);
            atomicAdd(&lsq[c8 + k],  q[k]);
        }
    }
    __syncthreads();
    if (tid < 128)       atomicAdd(&gsum[tid],      lsum[tid]);
    else                 atomicAdd(&gsq[tid - 128], lsq[tid - 128]);
}

// ---------------- Kernel B: streaming BN apply + SiLU + transpose writeout ----------------
__global__ __launch_bounds__(256) void k_apply(const ushort_t* __restrict__ abuf,
                                               const float* __restrict__ gsum,
                                               const float* __restrict__ gsq,
                                               const float* __restrict__ gamma,
                                               const float* __restrict__ beta,
                                               float* __restrict__ out) {
    int bi = blockIdx.x;          // 4608 = 4 * 1152
    int b  = bi / ROWS;
    int r  = bi % ROWS;

    __shared__ float scS[128];
    __shared__ float shS[128];
    __shared__ float ybuf[32 * 133];   // conflict-free transpose tile

    int tid = threadIdx.x;
    if (tid < 128) {
        const float cnt = (float)(NB * ROWS * IMW);  // 589824
        float m  = gsum[tid] / cnt;
        float vv = gsq[tid] / cnt - m * m;
        float inv = rsqrtf(fmaxf(vv, 0.f) + 1e-5f);
        float sc = inv * gamma[tid];
        scS[tid] = sc;
        shS[tid] = beta[tid] - m * sc;
    }
    __syncthreads();

    int g16 = tid >> 4;              // 0..15: w sub-slot
    int c8  = (tid & 15) << 3;       // 8 consecutive channels
    float scv[8], shv[8];
    *(float4*)&scv[0] = *(const float4*)&scS[c8];
    *(float4*)&scv[4] = *(const float4*)&scS[c8 + 4];
    *(float4*)&shv[0] = *(const float4*)&shS[c8];
    *(float4*)&shv[4] = *(const float4*)&shS[c8 + 4];

    const ushort_t* ar = abuf + ((size_t)(b * ROWS + r)) * IMW * NOUT + c8;
    float* outr = out + (size_t)b * NOUT * CHS + (size_t)r * IMW;

#pragma unroll
    for (int chunk = 0; chunk < 4; ++chunk) {
        int w0 = chunk << 5;
        // linear bf16 read + BN + SiLU -> LDS (2 w-slots per thread)
        {
            u32x4 va = *(const u32x4*)(ar + (size_t)(w0 + g16) * NOUT);
            u32x4 vb = *(const u32x4*)(ar + (size_t)(w0 + 16 + g16) * NOUT);
            float fa[8], fb[8];
            cvt8(va, fa); cvt8(vb, fb);
            float oa[8], ob[8];
#pragma unroll
            for (int k = 0; k < 8; ++k) {
                float t = fa[k] * scv[k] + shv[k];
                oa[k] = t / (1.f + __expf(-t));
                float u = fb[k] * scv[k] + shv[k];
                ob[k] = u / (1.f + __expf(-u));
            }
            float* d0 = &ybuf[g16 * 133 + c8];
            float* d1 = &ybuf[(16 + g16) * 133 + c8];
            *(float4*)d0       = *(float4*)&oa[0];
            *(float4*)(d0 + 4) = *(float4*)&oa[4];
            *(float4*)d1       = *(float4*)&ob[0];
            *(float4*)(d1 + 4) = *(float4*)&ob[4];
        }
        __syncthreads();
        // writeout: LDS transpose, coalesced NT float4 over w
#pragma unroll
        for (int i = 0; i < 4; ++i) {
            int task = (i << 8) + tid;     // 0..1023
            int oc   = task >> 3;
            int w4   = (task & 7) << 2;
            f32x4 v;
            v.x = ybuf[(w4 + 0) * 133 + oc];
            v.y = ybuf[(w4 + 1) * 133 + oc];
            v.z = ybuf[(w4 + 2) * 133 + oc];
            v.w = ybuf[(w4 + 3) * 133 + oc];
            __builtin_nontemporal_store(v, (f32x4*)(outr + (size_t)oc * CHS + w0 + w4));
        }
        __syncthreads();
    }
}

extern "C" void kernel_launch(void* const* d_in, const int* in_sizes, int n_in,
                              void* d_out, int out_size, void* d_ws, size_t ws_size,
                              hipStream_t stream) {
    const float* x     = (const float*)d_in[0];
    const float* pw    = (const float*)d_in[1];
    const float* pb    = (const float*)d_in[2];
    const float* cw    = (const float*)d_in[3];
    const float* gamma = (const float*)d_in[4];
    const float* beta  = (const float*)d_in[5];
    // d_in[6]/d_in[7] (attn_w/attn_b): dead code in the reference — unused.

    float* out = (float*)d_out;
    float* ws  = (float*)d_ws;

    float*    off  = ws;                                       // 1,179,648 f   (4.7 MB)
    ushort_t* z    = (ushort_t*)(off + (size_t)NB * 18 * HW);  // 8,388,608 bf16 (16.8 MB)
    ushort_t* abuf = z + (size_t)NB * HW * NOUT;               // 75,497,472 bf16 (151 MB)
    float*    gsum = (float*)(abuf + (size_t)NB * ROWS * IMW * NOUT); // 128 f
    float*    gsq  = gsum + NOUT;                              // 128 f

    hipLaunchKernelGGL(k_offset, dim3(1024), dim3(256), 0, stream, x, pw, pb, off, gsum);
    hipLaunchKernelGGL(k_z,      dim3(512),  dim3(256), 0, stream, x, cw, z);
    hipLaunchKernelGGL(k_gather, dim3(4608), dim3(256), 0, stream, off, z, abuf, gsum, gsq);
    hipLaunchKernelGGL(k_apply,  dim3(4608), dim3(256), 0, stream, abuf, gsum, gsq, gamma, beta, out);
}

// Round 9
// 303.316 us; speedup vs baseline: 1.1129x; 1.1129x over previous
//
#include <hip/hip_runtime.h>

#define CIN   64
#define NOUT  128
#define IMH   128
#define IMW   128
#define NPTS  9
#define NB    4
#define HW    (IMH*IMW)          // 16384
#define ROWS  (IMH*NPTS)         // 1152
#define CHS   (ROWS*IMW)         // 147456

typedef float f32x4 __attribute__((ext_vector_type(4)));
typedef unsigned short ushort_t;

// fp32 -> bf16 round-to-nearest-even
__device__ __forceinline__ ushort_t f2bf(float f) {
    union { float f; unsigned u; } a; a.f = f;
    unsigned r = a.u + 0x7FFFu + ((a.u >> 16) & 1u);
    return (ushort_t)(r >> 16);
}

// 8 packed bf16 (uint4) -> 8 fp32
__device__ __forceinline__ void cvt8(uint4 v, float* f) {
    f[0] = __uint_as_float(v.x << 16); f[1] = __uint_as_float(v.x & 0xFFFF0000u);
    f[2] = __uint_as_float(v.y << 16); f[3] = __uint_as_float(v.y & 0xFFFF0000u);
    f[4] = __uint_as_float(v.z << 16); f[5] = __uint_as_float(v.z & 0xFFFF0000u);
    f[6] = __uint_as_float(v.w << 16); f[7] = __uint_as_float(v.w & 0xFFFF0000u);
}

// ---------------- Kernel A: 3x3 SAME conv, C=64 -> 18 (offsets) ----------------
// Block 0 also zeroes the 256-float BN stats region (saves a memset dispatch).
__global__ __launch_bounds__(256) void k_offset(const float* __restrict__ x,
                                                const float* __restrict__ pw,
                                                const float* __restrict__ pb,
                                                float* __restrict__ off,
                                                float* __restrict__ stats0) {
    __shared__ float wl[576 * 20];        // [c*9+tap][k], stride 20 (float4-aligned)
    __shared__ float red[3 * 64 * 19];    // partials from cg=1..3

    int tid = threadIdx.x;
    if (blockIdx.x == 0) stats0[tid] = 0.f;   // gsum[128] + gsq[128]

    for (int t = tid; t < 18 * 576; t += 256) {
        int k = t / 576, cj = t % 576;    // pw layout [k][c][3][3]
        wl[cj * 20 + k] = pw[t];
    }
    __syncthreads();

    int cg = tid >> 6;        // 0..3 -> channel group
    int lp = tid & 63;        // pixel within block
    int gid = blockIdx.x * 64 + lp;
    int b = gid >> 14;
    int hw = gid & 16383;
    int h = hw >> 7;
    int w = hw & 127;

    float acc[18];
#pragma unroll
    for (int k = 0; k < 18; ++k) acc[k] = (cg == 0) ? pb[k] : 0.f;

    const float* xb = x + (size_t)b * CIN * HW;
    int c0 = cg * 16;
    for (int c = c0; c < c0 + 16; ++c) {
        const float* xc = xb + c * HW;
#pragma unroll
        for (int dh = 0; dh < 3; ++dh) {
            int hh = h + dh - 1;
            if ((unsigned)hh >= 128u) continue;
#pragma unroll
            for (int dw = 0; dw < 3; ++dw) {
                int ww = w + dw - 1;
                if ((unsigned)ww >= 128u) continue;
                float xv = xc[hh * IMW + ww];
                const float* wr = &wl[(c * 9 + dh * 3 + dw) * 20];
                float wv[18];
                *(float4*)&wv[0]  = *(const float4*)(wr);
                *(float4*)&wv[4]  = *(const float4*)(wr + 4);
                *(float4*)&wv[8]  = *(const float4*)(wr + 8);
                *(float4*)&wv[12] = *(const float4*)(wr + 12);
                *(float2*)&wv[16] = *(const float2*)(wr + 16);
#pragma unroll
                for (int k = 0; k < 18; ++k) acc[k] += wv[k] * xv;
            }
        }
    }

    if (cg > 0) {
        float* rp = &red[((cg - 1) * 64 + lp) * 19];
#pragma unroll
        for (int k = 0; k < 18; ++k) rp[k] = acc[k];
    }
    __syncthreads();
    if (cg == 0) {
#pragma unroll
        for (int k = 0; k < 18; ++k)
            acc[k] += red[(0 * 64 + lp) * 19 + k] + red[(64 + lp) * 19 + k] + red[(128 + lp) * 19 + k];
        float* ob = off + (size_t)b * 18 * HW + hw;
#pragma unroll
        for (int k = 0; k < 18; ++k) ob[k * HW] = acc[k];
    }
}

// ---------------- Kernel Z: 1x1 conv, x[b][c][hw] -> z[b][hw][oc] (bf16) ----------------
__global__ __launch_bounds__(256) void k_z(const float* __restrict__ x,
                                           const float* __restrict__ cw,
                                           ushort_t* __restrict__ z) {
    __shared__ float xs[64 * 128];   // [c][hw_local]
    __shared__ float wsm[64 * 128];  // [c][oc]
    int tid = threadIdx.x;
    int b   = blockIdx.x >> 7;
    int hw0 = (blockIdx.x & 127) << 7;

    const float* xb = x + (size_t)b * CIN * HW + hw0;
#pragma unroll
    for (int i = 0; i < 32; ++i) {
        int t = tid + i * 256;
        int c = t >> 7, l = t & 127;
        xs[t] = xb[c * HW + l];
    }
#pragma unroll
    for (int i = 0; i < 32; ++i) {
        int t = tid + i * 256;
        int oc = t & 127, c = t >> 7;        // cw layout [oc][c]
        wsm[c * 128 + oc] = cw[oc * 64 + c];
    }
    __syncthreads();

    int hw4  = (tid & 31) << 2;
    int oc16 = (tid >> 5) << 4;

    float acc[4][16];
#pragma unroll
    for (int j = 0; j < 4; ++j)
#pragma unroll
        for (int k = 0; k < 16; ++k) acc[j][k] = 0.f;

    for (int c = 0; c < 64; ++c) {
        float4 xv = *(const float4*)&xs[c * 128 + hw4];
        float xq[4] = {xv.x, xv.y, xv.z, xv.w};
        float wv[16];
        const float4* wrow = (const float4*)&wsm[c * 128 + oc16];
#pragma unroll
        for (int m = 0; m < 4; ++m) ((float4*)wv)[m] = wrow[m];
#pragma unroll
        for (int j = 0; j < 4; ++j)
#pragma unroll
            for (int k = 0; k < 16; ++k) acc[j][k] += xq[j] * wv[k];
    }

#pragma unroll
    for (int j = 0; j < 4; ++j) {
        ushort_t* zr = z + ((size_t)b * HW + hw0 + hw4 + j) * NOUT + oc16;
        union { ushort_t u[16]; uint4 q[2]; } pk;
#pragma unroll
        for (int k = 0; k < 16; ++k) pk.u[k] = f2bf(acc[j][k]);
        *(uint4*)zr       = pk.q[0];
        *(uint4*)(zr + 8) = pk.q[1];
    }
}

// ---------------- shared device helper: bilinear coords for one (b,h,n,w) ----------------
__device__ __forceinline__ void bilin_setup(const float* __restrict__ off,
                                            int b, int h, int n, int w,
                                            float4& g, int4& id) {
    const float* ob = off + ((size_t)b * 18 + n) * HW + h * IMW + w;
    float ox = ob[0];
    float oy = ob[9 * HW];
    float px = ox + (float)(n / 3) + (float)h;
    float py = oy + (float)(n % 3) + (float)w;
    float fX = floorf(px), fY = floorf(py);
    float fx = px - fX, fy = py - fY;
    int X = (int)fX, Y = (int)fY;
    g.x = (1.f - fx) * (1.f - fy);   // lt (X,   Y)
    g.y = fx * fy;                   // rb (X+1, Y+1)
    g.z = (1.f - fx) * fy;           // lb (X,   Y+1)
    g.w = fx * (1.f - fy);           // rt (X+1, Y)
    id.x = min(max(X * IMW + Y, 0), HW - 1) * NOUT;
    id.y = min(max((X + 1) * IMW + (Y + 1), 0), HW - 1) * NOUT;
    id.z = min(max(X * IMW + (Y + 1), 0), HW - 1) * NOUT;
    id.w = min(max((X + 1) * IMW + Y, 0), HW - 1) * NOUT;
}

// XCD-aware bijective swizzle: 4608 = 8 XCDs x 576 contiguous logical blocks.
__device__ __forceinline__ int swz_block() {
    return (blockIdx.x & 7) * 576 + (blockIdx.x >> 3);
}

// ---------------- Kernel S: gather pass 1 — BN sums, 8ch/lane bf16, wave-reduced ----------------
__global__ __launch_bounds__(256) void k_sum(const float* __restrict__ off,
                                             const ushort_t* __restrict__ z,
                                             float* __restrict__ gsum,
                                             float* __restrict__ gsq) {
    int logical = swz_block();
    int n  = logical % 9;
    int t2 = logical / 9;
    int h  = t2 & 127;
    int b  = t2 >> 7;

    __shared__ float4 gS[128];
    __shared__ int4   iS[128];
    __shared__ float  lsum[128];
    __shared__ float  lsq[128];

    int tid = threadIdx.x;
    if (tid < 128) {
        lsum[tid] = 0.f; lsq[tid] = 0.f;
        float4 g; int4 id;
        bilin_setup(off, b, h, n, tid, g, id);
        gS[tid] = g; iS[tid] = id;
    }
    __syncthreads();

    int g16 = tid >> 4;              // 0..15: w sub-slot
    int c8  = (tid & 15) << 3;       // 8 consecutive channels
    const ushort_t* zb = z + (size_t)b * HW * NOUT + c8;

    float s[8], q[8];
#pragma unroll
    for (int k = 0; k < 8; ++k) { s[k] = 0.f; q[k] = 0.f; }

    uint4 plt, prb, plb, prt;
    {
        int4 id = iS[g16];
        plt = *(const uint4*)(zb + id.x);
        prb = *(const uint4*)(zb + id.y);
        plb = *(const uint4*)(zb + id.z);
        prt = *(const uint4*)(zb + id.w);
    }
#pragma unroll
    for (int wi = 0; wi < 8; ++wi) {
        uint4 nlt, nrb, nlb, nrt;
        if (wi < 7) {
            int4 idn = iS[((wi + 1) << 4) + g16];
            nlt = *(const uint4*)(zb + idn.x);
            nrb = *(const uint4*)(zb + idn.y);
            nlb = *(const uint4*)(zb + idn.z);
            nrt = *(const uint4*)(zb + idn.w);
        }
        float4 g = gS[(wi << 4) + g16];
        float flt[8], frb[8], flb[8], frt[8];
        cvt8(plt, flt); cvt8(prb, frb); cvt8(plb, flb); cvt8(prt, frt);
#pragma unroll
        for (int k = 0; k < 8; ++k) {
            float a = g.x * flt[k] + g.y * frb[k] + g.z * flb[k] + g.w * frt[k];
            s[k] += a; q[k] += a * a;
        }
        plt = nlt; prb = nrb; plb = nlb; prt = nrt;
    }

#pragma unroll
    for (int k = 0; k < 8; ++k) {
        s[k] += __shfl_xor(s[k], 16, 64); s[k] += __shfl_xor(s[k], 32, 64);
        q[k] += __shfl_xor(q[k], 16, 64); q[k] += __shfl_xor(q[k], 32, 64);
    }
    if (((tid >> 4) & 3) == 0) {
#pragma unroll
        for (int k = 0; k < 8; ++k) {
            atomicAdd(&lsum[c8 + k], s[k]);
            atomicAdd(&lsq[c8 + k],  q[k]);
        }
    }
    __syncthreads();
    if (tid < 128)       atomicAdd(&gsum[tid],      lsum[tid]);
    else                 atomicAdd(&gsq[tid - 128], lsq[tid - 128]);
}

// ---------------- k_apply helper: 4 bf16 corners x 8ch -> BN -> SiLU -> LDS ----------------
__device__ __forceinline__ void proc8(const uint4* C, float4 g,
                                      const float* sc, const float* sh,
                                      float* __restrict__ dst) {
    float flt[8], frb[8], flb[8], frt[8];
    cvt8(C[0], flt); cvt8(C[1], frb); cvt8(C[2], flb); cvt8(C[3], frt);
    float o[8];
#pragma unroll
    for (int k = 0; k < 8; ++k) {
        float t = (g.x * flt[k] + g.y * frb[k] + g.z * flb[k] + g.w * frt[k]) * sc[k] + sh[k];
        o[k] = t / (1.f + __expf(-t));
    }
    *(float4*)dst       = *(float4*)&o[0];
    *(float4*)(dst + 4) = *(float4*)&o[4];
}

// ---------------- Kernel B: gather pass 2 — inline stats + dbuf gather + LDS transpose
//                  + BN apply + SiLU + nontemporal coalesced stores ----------------
__global__ __launch_bounds__(256) void k_apply(const float* __restrict__ off,
                                               const ushort_t* __restrict__ z,
                                               const float* __restrict__ gsum,
                                               const float* __restrict__ gsq,
                                               const float* __restrict__ gamma,
                                               const float* __restrict__ beta,
                                               float* __restrict__ out) {
    int logical = swz_block();
    int n  = logical % 9;
    int t2 = logical / 9;
    int h  = t2 & 127;
    int b  = t2 >> 7;

    __shared__ float4 gS[128];
    __shared__ int4   iS[128];
    __shared__ float  scS[128];
    __shared__ float  shS[128];
    __shared__ float  ybuf[2][32 * 133];   // stride 133: conflict-free transpose

    int tid = threadIdx.x;
    if (tid < 128) {
        float4 g; int4 id;
        bilin_setup(off, b, h, n, tid, g, id);
        gS[tid] = g; iS[tid] = id;
    } else {
        int c = tid - 128;
        const float cnt = (float)(NB * ROWS * IMW);  // 589824
        float m  = gsum[c] / cnt;
        float vv = gsq[c] / cnt - m * m;
        float inv = rsqrtf(fmaxf(vv, 0.f) + 1e-5f);
        float sc = inv * gamma[c];
        scS[c] = sc;
        shS[c] = beta[c] - m * sc;
    }
    __syncthreads();

    int g16 = tid >> 4;              // 0..15: w sub-slot
    int c8  = (tid & 15) << 3;       // 8 consecutive channels
    float scv[8], shv[8];
    *(float4*)&scv[0] = *(const float4*)&scS[c8];
    *(float4*)&scv[4] = *(const float4*)&scS[c8 + 4];
    *(float4*)&shv[0] = *(const float4*)&shS[c8];
    *(float4*)&shv[4] = *(const float4*)&shS[c8 + 4];

    const ushort_t* zb = z + (size_t)b * HW * NOUT + c8;
    int r = h * 9 + n;
    float* outr = out + (size_t)b * NOUT * CHS + (size_t)r * IMW;

    uint4 A[8];
#define STAGE(wb) { int4 _i0 = iS[(wb) + g16]; int4 _i1 = iS[(wb) + 16 + g16]; \
    A[0] = *(const uint4*)(zb + _i0.x); A[1] = *(const uint4*)(zb + _i0.y); \
    A[2] = *(const uint4*)(zb + _i0.z); A[3] = *(const uint4*)(zb + _i0.w); \
    A[4] = *(const uint4*)(zb + _i1.x); A[5] = *(const uint4*)(zb + _i1.y); \
    A[6] = *(const uint4*)(zb + _i1.z); A[7] = *(const uint4*)(zb + _i1.w); }
#define PROC(wb, bi) { \
    proc8(&A[0], gS[(wb) + g16],      scv, shv, &ybuf[bi][g16 * 133 + c8]); \
    proc8(&A[4], gS[(wb) + 16 + g16], scv, shv, &ybuf[bi][(16 + g16) * 133 + c8]); }

    // prologue: chunk 0 into buf 0
    STAGE(0);
    PROC(0, 0);
    __syncthreads();

#pragma unroll
    for (int chunk = 0; chunk < 4; ++chunk) {
        const int cur = chunk & 1;
        const int nxt = cur ^ 1;
        int w0 = chunk << 5;

        if (chunk < 3) STAGE(w0 + 32);   // issue next chunk's loads early

        // writeout current chunk: LDS transpose, coalesced NT float4 over w
#pragma unroll
        for (int i = 0; i < 4; ++i) {
            int task = (i << 8) + tid;     // 0..1023
            int oc   = task >> 3;
            int w4   = (task & 7) << 2;
            f32x4 v;
            v.x = ybuf[cur][(w4 + 0) * 133 + oc];
            v.y = ybuf[cur][(w4 + 1) * 133 + oc];
            v.z = ybuf[cur][(w4 + 2) * 133 + oc];
            v.w = ybuf[cur][(w4 + 3) * 133 + oc];
            __builtin_nontemporal_store(v, (f32x4*)(outr + (size_t)oc * CHS + w0 + w4));
        }

        if (chunk < 3) PROC(w0 + 32, nxt);
        __syncthreads();
    }
#undef STAGE
#undef PROC
}

extern "C" void kernel_launch(void* const* d_in, const int* in_sizes, int n_in,
                              void* d_out, int out_size, void* d_ws, size_t ws_size,
                              hipStream_t stream) {
    const float* x     = (const float*)d_in[0];
    const float* pw    = (const float*)d_in[1];
    const float* pb    = (const float*)d_in[2];
    const float* cw    = (const float*)d_in[3];
    const float* gamma = (const float*)d_in[4];
    const float* beta  = (const float*)d_in[5];
    // d_in[6]/d_in[7] (attn_w/attn_b): dead code in the reference — unused.

    float* out = (float*)d_out;
    float* ws  = (float*)d_ws;

    float*    off  = ws;                                     // 1,179,648 f  (4.7 MB)
    ushort_t* z    = (ushort_t*)(off + (size_t)NB * 18 * HW);// 8,388,608 bf16 (16.8 MB)
    float*    gsum = (float*)(z + (size_t)NB * HW * NOUT);   // 128 f
    float*    gsq  = gsum + NOUT;                            // 128 f

    hipLaunchKernelGGL(k_offset, dim3(1024), dim3(256), 0, stream, x, pw, pb, off, gsum);
    hipLaunchKernelGGL(k_z,      dim3(512),  dim3(256), 0, stream, x, cw, z);
    hipLaunchKernelGGL(k_sum,    dim3(4608), dim3(256), 0, stream, off, z, gsum, gsq);
    hipLaunchKernelGGL(k_apply,  dim3(4608), dim3(256), 0, stream, off, z, gsum, gsq, gamma, beta, out);
}